// Round 1
// baseline (311.655 us; speedup 1.0000x reference)
//
#include <hip/hip_runtime.h>
#include <math.h>

// Problem constants (from reference): B=4, N=4096, V=4096, P=16, C=16, NK=4, L_MAX=2
#define V_DIM 4096
#define N_DIM 4096

// ---------------------------------------------------------------------------
// Clebsch-Gordan table build (Racah formula, mirrors reference _cg exactly).
// 12 (l,k,J) tables, dense [2J+1][2l+1][2k+1], total 580 floats in d_ws.
// Offsets: (1,0,1)@0 (1,1,0)@9 (1,1,1)@18 (1,1,2)@45 (1,2,1)@90 (1,2,2)@135
//          (2,0,2)@210 (2,1,1)@235 (2,1,2)@280 (2,2,0)@355 (2,2,1)@380 (2,2,2)@455
// ---------------------------------------------------------------------------
__device__ inline double dfac(int x){ double r=1.0; for(int i=2;i<=x;++i) r*=(double)i; return r; }

__global__ void build_q_kernel(float* __restrict__ Qt){
  int tid = blockIdx.x*blockDim.x + threadIdx.x;
  if(tid >= 580) return;
  const int Lc[12]={1,1,1,1,1,1,2,2,2,2,2,2};
  const int Kc[12]={0,1,1,1,2,2,0,1,1,2,2,2};
  const int Jc[12]={1,0,1,2,1,2,2,1,2,0,1,2};
  const int SZ[12]={9,9,27,45,45,75,25,45,75,25,75,125};
  int ci=0, rem=tid;
  while(rem >= SZ[ci]){ rem -= SZ[ci]; ++ci; }
  const int l=Lc[ci], k=Kc[ci], J=Jc[ci];
  const int tk=2*k+1, tl=2*l+1;
  const int n = rem % tk - k;
  const int m = (rem / tk) % tl - l;
  const int M = rem / (tk*tl) - J;
  float val = 0.f;
  if(M == m+n){
    double pref = (double)(2*J+1) * dfac(l+k-J)*dfac(l-k+J)*dfac(-l+k+J)/dfac(l+k+J+1);
    pref *= dfac(J+M)*dfac(J-M)*dfac(l-m)*dfac(l+m)*dfac(k-n)*dfac(k+n);
    int tlo = max(0, max(k-J-m, l+n-J));
    int thi = min(l+k-J, min(l-m, k+n));
    double s = 0.0;
    for(int tt=tlo; tt<=thi; ++tt){
      double d = dfac(tt)*dfac(l+k-J-tt)*dfac(l-m-tt)*dfac(k+n-tt)*dfac(J-k+m+tt)*dfac(J-l-n+tt);
      s += ((tt&1)? -1.0 : 1.0)/d;
    }
    val = (float)(sqrt(pref)*s);
  }
  Qt[tid] = val;
}

// Detect whether patches_idx is int64 (stride 2 dwords/value) or int32 (stride 1).
// int64 layout: every odd dword is a zero high-half (values are small nonneg).
__global__ void detect_kernel(const unsigned* __restrict__ pw, int* __restrict__ flag){
  unsigned acc = 0u;
  for(int i=0;i<32;++i) acc |= pw[2*i+1];
  *flag = (acc==0u) ? 2 : 1;
}

// ---------------------------------------------------------------------------
// Main kernel: one 64-thread block per (b,v). Thread t: n = t>>4, c = t&15.
// y[mglob][kdglob] accumulates sum_p kern[p][kd][n]*sig[p][m][c].
// mglob/kdglob: l=0 -> 0, l=1 -> 1..3, l=2 -> 4..8.
// ---------------------------------------------------------------------------

template<int L_, int K_, int J_, int OFF_, int W_, int CHOFF_>
__device__ __forceinline__ void cg_out(const float* __restrict__ Qt,
                                       const float (&y)[9][9],
                                       float* __restrict__ optr,
                                       size_t bvs, int t){
  constexpr int MGB = (L_==0)?0:((L_==1)?1:4);
  constexpr int KGB = (K_==0)?0:((K_==1)?1:4);
  #pragma unroll
  for(int M=-J_; M<=J_; ++M){
    float acc = 0.f;
    #pragma unroll
    for(int m=-L_; m<=L_; ++m){
      const int nn = M - m;               // CG selection rule
      if(nn < -K_ || nn > K_) continue;
      const float q = Qt[OFF_ + ((M+J_)*(2*L_+1) + (m+L_))*(2*K_+1) + (nn+K_)];
      acc += q * y[MGB + m + L_][KGB + nn + K_];
    }
    optr[(bvs*(2*J_+1) + (size_t)(M+J_))*W_ + CHOFF_ + t] = acc;
  }
}

__global__ __launch_bounds__(64)
void conv_kernel(const float* __restrict__ sig0, const float* __restrict__ ker0,
                 const float* __restrict__ sig1, const float* __restrict__ ker1,
                 const float* __restrict__ sig2, const float* __restrict__ ker2,
                 const unsigned* __restrict__ pw, const int* __restrict__ flag,
                 const float* __restrict__ Qt, float* __restrict__ out){
  __shared__ __align__(16) float sig_lds[16*144];   // [p][mglob(9)][c(16)]
  __shared__ __align__(16) float kern_lds[16*9*4];  // [p][kdglob(9)][n(4)]
  __shared__ int pn_s[16], pb_s[16];

  const int t  = threadIdx.x;
  const int bv = blockIdx.x;            // b*V + v
  const size_t bvs = (size_t)bv;

  // --- patch indices (handles int64 or int32 storage) ---
  if(t < 16){
    const int s = *flag;                              // 2 = int64, 1 = int32
    const size_t e = ((size_t)bv*16 + t)*2;
    pb_s[t] = (int)pw[(e+0)*s] & 3;
    pn_s[t] = (int)pw[(e+1)*s] & (N_DIM-1);
  }

  // --- stage kernels (coalesced float4) ---
  {
    const float4* s4 = (const float4*)(ker0 + bvs*16*1*4);
    for(int j=t; j<16; j+=64){ ((float4*)kern_lds)[j*9 + 0] = s4[j]; }
    s4 = (const float4*)(ker1 + bvs*16*3*4);
    for(int j=t; j<48; j+=64){ int p=j/3, kd=j%3; ((float4*)kern_lds)[p*9 + 1 + kd] = s4[j]; }
    s4 = (const float4*)(ker2 + bvs*16*5*4);
    for(int j=t; j<80; j+=64){ int p=j/5, kd=j%5; ((float4*)kern_lds)[p*9 + 4 + kd] = s4[j]; }
  }
  __syncthreads();

  // --- gather signals into LDS: 16 patches x 36 float4 each ---
  for(int i=t; i<16*36; i+=64){
    const int p = i/36, r4 = i%36;
    const size_t row = (size_t)pb_s[p]*N_DIM + pn_s[p];
    float4 v4;
    if(r4 < 4)        v4 = ((const float4*)(sig0 + row*16))[r4];
    else if(r4 < 16)  v4 = ((const float4*)(sig1 + row*48))[r4-4];
    else              v4 = ((const float4*)(sig2 + row*80))[r4-16];
    ((float4*)sig_lds)[p*36 + r4] = v4;
  }
  __syncthreads();

  // --- main contraction over patches ---
  const int n = t >> 4, c = t & 15;
  float y[9][9];
  #pragma unroll
  for(int a=0;a<9;++a)
    #pragma unroll
    for(int b_=0;b_<9;++b_) y[a][b_] = 0.f;

  #pragma unroll
  for(int p=0;p<16;++p){
    float s[9], kk[9];
    #pragma unroll
    for(int m=0;m<9;++m)  s[m]  = sig_lds[p*144 + m*16 + c];
    #pragma unroll
    for(int kd=0;kd<9;++kd) kk[kd] = kern_lds[(p*9 + kd)*4 + n];
    #pragma unroll
    for(int m=0;m<9;++m)
      #pragma unroll
      for(int kd=0;kd<9;++kd) y[m][kd] += s[m]*kk[kd];
  }

  // --- outputs ---
  // d_out: out0 [B*V][1][192] @0 ; out1 [B*V][3][384] @3145728 ; out2 [B*V][5][384] @22020096
  float* o0 = out;
  float* o1 = out + 3145728;
  float* o2 = out + 22020096;

  // l=0 direct contributions (channel offset 0 in each output)
  o0[bvs*192 + t] = y[0][0];
  #pragma unroll
  for(int kd=0;kd<3;++kd) o1[(bvs*3 + kd)*384 + t] = y[0][1+kd];
  #pragma unroll
  for(int kd=0;kd<5;++kd) o2[(bvs*5 + kd)*384 + t] = y[0][4+kd];

  // CG contributions. Channel offsets follow reference concat order.
  // J=0 (out0, W=192): (1,1)@64, (2,2)@128
  cg_out<1,1,0,  9,192, 64>(Qt, y, o0, bvs, t);
  cg_out<2,2,0,355,192,128>(Qt, y, o0, bvs, t);
  // J=1 (out1, W=384): (1,0)@64, (1,1)@128, (1,2)@192, (2,1)@256, (2,2)@320
  cg_out<1,0,1,  0,384, 64>(Qt, y, o1, bvs, t);
  cg_out<1,1,1, 18,384,128>(Qt, y, o1, bvs, t);
  cg_out<1,2,1, 90,384,192>(Qt, y, o1, bvs, t);
  cg_out<2,1,1,235,384,256>(Qt, y, o1, bvs, t);
  cg_out<2,2,1,380,384,320>(Qt, y, o1, bvs, t);
  // J=2 (out2, W=384): (1,1)@64, (1,2)@128, (2,0)@192, (2,1)@256, (2,2)@320
  cg_out<1,1,2, 45,384, 64>(Qt, y, o2, bvs, t);
  cg_out<1,2,2,135,384,128>(Qt, y, o2, bvs, t);
  cg_out<2,0,2,210,384,192>(Qt, y, o2, bvs, t);
  cg_out<2,1,2,280,384,256>(Qt, y, o2, bvs, t);
  cg_out<2,2,2,455,384,320>(Qt, y, o2, bvs, t);
}

extern "C" void kernel_launch(void* const* d_in, const int* in_sizes, int n_in,
                              void* d_out, int out_size, void* d_ws, size_t ws_size,
                              hipStream_t stream) {
  // Expected dict order: signal_0, kernel_0, signal_1, kernel_1, signal_2, kernel_2, patches_idx
  const float *s0=nullptr,*s1=nullptr,*s2=nullptr,*k0=nullptr,*k1=nullptr,*k2=nullptr;
  const void* pidx=nullptr;
  // Positional fallback (dict order)
  if(n_in >= 7){
    s0=(const float*)d_in[0]; k0=(const float*)d_in[1];
    s1=(const float*)d_in[2]; k1=(const float*)d_in[3];
    s2=(const float*)d_in[4]; k2=(const float*)d_in[5];
    pidx=d_in[6];
  }
  // Robust size-based matching (all sizes distinct)
  for(int i=0;i<n_in;++i){
    switch(in_sizes[i]){
      case 262144:  s0=(const float*)d_in[i]; break;   // 4*4096*1*16
      case 786432:  s1=(const float*)d_in[i]; break;   // 4*4096*3*16
      case 1310720: s2=(const float*)d_in[i]; break;   // 4*4096*5*16
      case 1048576: k0=(const float*)d_in[i]; break;   // 4*4096*16*1*4
      case 3145728: k1=(const float*)d_in[i]; break;   // 4*4096*16*3*4
      case 5242880: k2=(const float*)d_in[i]; break;   // 4*4096*16*5*4
      case 524288:  pidx=d_in[i]; break;               // 4*4096*16*2
      default: break;
    }
  }

  float* Qt  = (float*)d_ws;                     // 580 floats
  int* flag  = (int*)((char*)d_ws + 4096);       // layout flag

  build_q_kernel<<<3, 256, 0, stream>>>(Qt);
  detect_kernel<<<1, 1, 0, stream>>>((const unsigned*)pidx, flag);
  conv_kernel<<<16384, 64, 0, stream>>>(s0, k0, s1, k1, s2, k2,
                                        (const unsigned*)pidx, flag, Qt,
                                        (float*)d_out);
}

// Round 2
// 289.219 us; speedup vs baseline: 1.0776x; 1.0776x over previous
//
#include <hip/hip_runtime.h>
#include <math.h>

// Problem constants: B=4, N=4096, V=4096, P=16, C=16, NK=4, L_MAX=2
#define V_DIM 4096
#define N_DIM 4096

// ---------------------------------------------------------------------------
// Setup: CG table (Racah formula, mirrors reference _cg) + idx-width detect.
// Q tables dense [2J+1][2l+1][2k+1], 580 floats total, offsets:
// (1,0,1)@0 (1,1,0)@9 (1,1,1)@18 (1,1,2)@45 (1,2,1)@90 (1,2,2)@135
// (2,0,2)@210 (2,1,1)@235 (2,1,2)@280 (2,2,0)@355 (2,2,1)@380 (2,2,2)@455
// ---------------------------------------------------------------------------
__device__ inline double dfac(int x){ double r=1.0; for(int i=2;i<=x;++i) r*=(double)i; return r; }

__global__ void setup_kernel(float* __restrict__ Qt,
                             const unsigned* __restrict__ pw,
                             int* __restrict__ flag){
  const int tid = threadIdx.x;
  if(tid == 1016){
    // int64 layout => every odd dword (high half) is zero for small nonneg values
    unsigned acc = 0u;
    for(int i=0;i<32;++i) acc |= pw[2*i+1];
    *flag = (acc==0u) ? 2 : 1;
    return;
  }
  if(tid >= 580) return;
  const int Lc[12]={1,1,1,1,1,1,2,2,2,2,2,2};
  const int Kc[12]={0,1,1,1,2,2,0,1,1,2,2,2};
  const int Jc[12]={1,0,1,2,1,2,2,1,2,0,1,2};
  const int SZ[12]={9,9,27,45,45,75,25,45,75,25,75,125};
  int ci=0, rem=tid;
  while(rem >= SZ[ci]){ rem -= SZ[ci]; ++ci; }
  const int l=Lc[ci], k=Kc[ci], J=Jc[ci];
  const int tk=2*k+1, tl=2*l+1;
  const int n = rem % tk - k;
  const int m = (rem / tk) % tl - l;
  const int M = rem / (tk*tl) - J;
  float val = 0.f;
  if(M == m+n){
    double pref = (double)(2*J+1) * dfac(l+k-J)*dfac(l-k+J)*dfac(-l+k+J)/dfac(l+k+J+1);
    pref *= dfac(J+M)*dfac(J-M)*dfac(l-m)*dfac(l+m)*dfac(k-n)*dfac(k+n);
    int tlo = max(0, max(k-J-m, l+n-J));
    int thi = min(l+k-J, min(l-m, k+n));
    double s = 0.0;
    for(int tt=tlo; tt<=thi; ++tt){
      double d = dfac(tt)*dfac(l+k-J-tt)*dfac(l-m-tt)*dfac(k+n-tt)*dfac(J-k+m+tt)*dfac(J-l-n+tt);
      s += ((tt&1)? -1.0 : 1.0)/d;
    }
    val = (float)(sqrt(pref)*s);
  }
  Qt[tid] = val;
}

// ---------------------------------------------------------------------------
// Main kernel: one 64-thread block (1 wave) per (b,v). Thread t: n=t>>4, c=t&15.
// y[mglob][kdglob] = sum_p kern[p][kd][n] * sig[p][m][c].
// mglob/kdglob: l(or k)=0 -> 0, =1 -> 1..3, =2 -> 4..8.
// LDS: sig_lds [p][m][c] (float4 chunks), kern_t [p][n][12] (kd 0..8, padded)
// ---------------------------------------------------------------------------

template<int L_, int K_, int J_, int OFF_, int W_, int CHOFF_>
__device__ __forceinline__ void cg_out(const float* __restrict__ Qt,
                                       const float (&y)[9][9],
                                       float* __restrict__ optr,
                                       size_t bvs, int t){
  constexpr int MGB = (L_==0)?0:((L_==1)?1:4);
  constexpr int KGB = (K_==0)?0:((K_==1)?1:4);
  #pragma unroll
  for(int M=-J_; M<=J_; ++M){
    float acc = 0.f;
    #pragma unroll
    for(int m=-L_; m<=L_; ++m){
      const int nn = M - m;               // CG selection rule
      if(nn < -K_ || nn > K_) continue;
      const float q = Qt[OFF_ + ((M+J_)*(2*L_+1) + (m+L_))*(2*K_+1) + (nn+K_)];
      acc += q * y[MGB + m + L_][KGB + nn + K_];
    }
    optr[(bvs*(2*J_+1) + (size_t)(M+J_))*W_ + CHOFF_ + t] = acc;
  }
}

__global__ __launch_bounds__(64)
void conv_kernel(const float* __restrict__ sig0, const float* __restrict__ ker0,
                 const float* __restrict__ sig1, const float* __restrict__ ker1,
                 const float* __restrict__ sig2, const float* __restrict__ ker2,
                 const unsigned* __restrict__ pw, const int* __restrict__ flag,
                 const float* __restrict__ Qt, float* __restrict__ out){
  __shared__ __align__(16) float sig_lds[16*144];   // [p][m(9)][c(16)]
  __shared__ __align__(16) float kern_t[16*48];     // [p][n(4)][12] kd 0..8
  __shared__ int pn_s[16], pb_s[16];

  const int t  = threadIdx.x;
  const int bv = blockIdx.x;            // b*V + v
  const size_t bvs = (size_t)bv;

  // --- patch indices first (latency overlapped with kernel staging) ---
  if(t < 16){
    const int s = *flag;                              // 2 = int64, 1 = int32
    const size_t e = ((size_t)bv*16 + t)*2;
    pb_s[t] = (int)pw[(e+0)*s] & 3;
    pn_s[t] = (int)pw[(e+1)*s] & (N_DIM-1);
  }

  // --- stage kernels, transposed to [p][n][12] ---
  {
    if(t < 16){
      float4 v = ((const float4*)(ker0 + bvs*64))[t];        // [p][kd0][n0..3]
      float* d = &kern_t[t*48];
      d[0*12+0]=v.x; d[1*12+0]=v.y; d[2*12+0]=v.z; d[3*12+0]=v.w;
    }
    if(t < 48){
      float4 v = ((const float4*)(ker1 + bvs*192))[t];       // [p][kd][n]
      int p = t/3, kd = t%3;
      float* d = &kern_t[p*48 + 1 + kd];
      d[0*12]=v.x; d[1*12]=v.y; d[2*12]=v.z; d[3*12]=v.w;
    }
    #pragma unroll
    for(int j=t; j<80; j+=64){
      float4 v = ((const float4*)(ker2 + bvs*320))[j];
      int p = j/5, kd = j%5;
      float* d = &kern_t[p*48 + 4 + kd];
      d[0*12]=v.x; d[1*12]=v.y; d[2*12]=v.z; d[3*12]=v.w;
    }
  }
  __syncthreads();

  // --- gather signals: lane (p=t>>2, q=t&3), uniform source array per step ---
  {
    const int p = t>>2, q = t&3;
    const size_t row = (size_t)pb_s[p]*N_DIM + pn_s[p];
    const float4* r0 = (const float4*)(sig0 + row*16);
    const float4* r1 = (const float4*)(sig1 + row*48);
    const float4* r2 = (const float4*)(sig2 + row*80);
    float4* dst = ((float4*)sig_lds) + p*36;
    dst[q] = r0[q];
    #pragma unroll
    for(int j=1;j<4;++j)  dst[q+4*j] = r1[q+4*j-4];
    #pragma unroll
    for(int j=4;j<9;++j)  dst[q+4*j] = r2[q+4*j-16];
  }
  __syncthreads();

  // --- main contraction over patches ---
  const int n = t >> 4, c = t & 15;
  float y[9][9];
  #pragma unroll
  for(int a=0;a<9;++a)
    #pragma unroll
    for(int b_=0;b_<9;++b_) y[a][b_] = 0.f;

  #pragma unroll
  for(int p=0;p<16;++p){
    float kk[9];
    {
      float4 a = *(const float4*)&kern_t[p*48 + n*12];      // kd 0-3
      float4 b = *(const float4*)&kern_t[p*48 + n*12 + 4];  // kd 4-7
      kk[0]=a.x; kk[1]=a.y; kk[2]=a.z; kk[3]=a.w;
      kk[4]=b.x; kk[5]=b.y; kk[6]=b.z; kk[7]=b.w;
      kk[8]=kern_t[p*48 + n*12 + 8];
    }
    float s[9];
    #pragma unroll
    for(int m=0;m<9;++m)  s[m] = sig_lds[p*144 + m*16 + c];
    #pragma unroll
    for(int m=0;m<9;++m)
      #pragma unroll
      for(int kd=0;kd<9;++kd) y[m][kd] += s[m]*kk[kd];
  }

  // --- outputs ---
  // d_out: out0 [B*V][1][192] @0 ; out1 [B*V][3][384] @3145728 ; out2 [B*V][5][384] @22020096
  float* o0 = out;
  float* o1 = out + 3145728;
  float* o2 = out + 22020096;

  // l=0 direct contributions (channel offset 0 in each output)
  o0[bvs*192 + t] = y[0][0];
  #pragma unroll
  for(int kd=0;kd<3;++kd) o1[(bvs*3 + kd)*384 + t] = y[0][1+kd];
  #pragma unroll
  for(int kd=0;kd<5;++kd) o2[(bvs*5 + kd)*384 + t] = y[0][4+kd];

  // CG contributions; channel offsets follow reference concat order.
  // J=0 (out0, W=192): (1,1)@64, (2,2)@128
  cg_out<1,1,0,  9,192, 64>(Qt, y, o0, bvs, t);
  cg_out<2,2,0,355,192,128>(Qt, y, o0, bvs, t);
  // J=1 (out1, W=384): (1,0)@64, (1,1)@128, (1,2)@192, (2,1)@256, (2,2)@320
  cg_out<1,0,1,  0,384, 64>(Qt, y, o1, bvs, t);
  cg_out<1,1,1, 18,384,128>(Qt, y, o1, bvs, t);
  cg_out<1,2,1, 90,384,192>(Qt, y, o1, bvs, t);
  cg_out<2,1,1,235,384,256>(Qt, y, o1, bvs, t);
  cg_out<2,2,1,380,384,320>(Qt, y, o1, bvs, t);
  // J=2 (out2, W=384): (1,1)@64, (1,2)@128, (2,0)@192, (2,1)@256, (2,2)@320
  cg_out<1,1,2, 45,384, 64>(Qt, y, o2, bvs, t);
  cg_out<1,2,2,135,384,128>(Qt, y, o2, bvs, t);
  cg_out<2,0,2,210,384,192>(Qt, y, o2, bvs, t);
  cg_out<2,1,2,280,384,256>(Qt, y, o2, bvs, t);
  cg_out<2,2,2,455,384,320>(Qt, y, o2, bvs, t);
}

extern "C" void kernel_launch(void* const* d_in, const int* in_sizes, int n_in,
                              void* d_out, int out_size, void* d_ws, size_t ws_size,
                              hipStream_t stream) {
  const float *s0=nullptr,*s1=nullptr,*s2=nullptr,*k0=nullptr,*k1=nullptr,*k2=nullptr;
  const void* pidx=nullptr;
  if(n_in >= 7){
    s0=(const float*)d_in[0]; k0=(const float*)d_in[1];
    s1=(const float*)d_in[2]; k1=(const float*)d_in[3];
    s2=(const float*)d_in[4]; k2=(const float*)d_in[5];
    pidx=d_in[6];
  }
  for(int i=0;i<n_in;++i){
    switch(in_sizes[i]){
      case 262144:  s0=(const float*)d_in[i]; break;   // 4*4096*1*16
      case 786432:  s1=(const float*)d_in[i]; break;   // 4*4096*3*16
      case 1310720: s2=(const float*)d_in[i]; break;   // 4*4096*5*16
      case 1048576: k0=(const float*)d_in[i]; break;   // 4*4096*16*1*4
      case 3145728: k1=(const float*)d_in[i]; break;   // 4*4096*16*3*4
      case 5242880: k2=(const float*)d_in[i]; break;   // 4*4096*16*5*4
      case 524288:  pidx=d_in[i]; break;               // 4*4096*16*2
      default: break;
    }
  }

  float* Qt = (float*)d_ws;                     // 580 floats
  int* flag = (int*)((char*)d_ws + 4096);

  setup_kernel<<<1, 1024, 0, stream>>>(Qt, (const unsigned*)pidx, flag);
  conv_kernel<<<16384, 64, 0, stream>>>(s0, k0, s1, k1, s2, k2,
                                        (const unsigned*)pidx, flag, Qt,
                                        (float*)d_out);
}

// Round 3
// 288.680 us; speedup vs baseline: 1.0796x; 1.0019x over previous
//
#include <hip/hip_runtime.h>

// Problem constants: B=4, N=4096, V=4096, P=16, C=16, NK=4, L_MAX=2
#define N_DIM 4096

// ---------------------------------------------------------------------------
// Compile-time Clebsch-Gordan coefficients (Racah formula, mirrors reference)
// ---------------------------------------------------------------------------
constexpr double cfac(int x){ double r=1.0; for(int i=2;i<=x;++i) r*=(double)i; return r; }
constexpr double csqrt_(double x){ double g = x>1.0? x:1.0; for(int i=0;i<200;++i) g=0.5*(g+x/g); return g; }
constexpr double cg_coef(int l,int m,int k,int n,int J,int M){
  if(M != m+n) return 0.0;
  if(n < -k || n > k) return 0.0;
  double pref = (double)(2*J+1)*cfac(l+k-J)*cfac(l-k+J)*cfac(-l+k+J)/cfac(l+k+J+1);
  pref *= cfac(J+M)*cfac(J-M)*cfac(l-m)*cfac(l+m)*cfac(k-n)*cfac(k+n);
  int tlo = 0;
  if(k-J-m > tlo) tlo = k-J-m;
  if(l+n-J > tlo) tlo = l+n-J;
  int thi = l+k-J;
  if(l-m < thi) thi = l-m;
  if(k+n < thi) thi = k+n;
  double s = 0.0;
  for(int t=tlo; t<=thi; ++t){
    double d = cfac(t)*cfac(l+k-J-t)*cfac(l-m-t)*cfac(k+n-t)*cfac(J-k+m+t)*cfac(J-l-n+t);
    s += ((t&1)? -1.0 : 1.0)/d;
  }
  return csqrt_(pref)*s;
}

template<int L_,int K_,int J_> struct QtabT { float a[2*J_+1][2*L_+1]; };
template<int L_,int K_,int J_>
constexpr QtabT<L_,K_,J_> make_q(){
  QtabT<L_,K_,J_> q{};
  for(int M=-J_;M<=J_;++M)
    for(int m=-L_;m<=L_;++m)
      q.a[M+J_][m+L_] = (float)cg_coef(L_,m,K_,M-m,J_,M);
  return q;
}

// CG-project local y[2L+1][2K+1] into output degree J and store (coalesced 256B)
template<int L_,int K_,int J_,int W_,int CHOFF_>
__device__ __forceinline__ void cg_store(const float (&y)[2*L_+1][2*K_+1],
                                         float* __restrict__ o, size_t bvs, int lane){
  constexpr QtabT<L_,K_,J_> Q = make_q<L_,K_,J_>();
  #pragma unroll
  for(int Mi=0; Mi<2*J_+1; ++Mi){
    float acc = 0.f;
    #pragma unroll
    for(int mi=0; mi<2*L_+1; ++mi){
      const int ni = (Mi-J_) - (mi-L_) + K_;     // CG selection rule n = M-m
      if(ni < 0 || ni > 2*K_) continue;
      acc += Q.a[Mi][mi] * y[mi][ni];
    }
    o[(bvs*(2*J_+1) + (size_t)Mi)*W_ + CHOFF_ + lane] = acc;
  }
}

// ---------------------------------------------------------------------------
// Main kernel: 256 threads = 4 waves per (b,v). LDS staged once, shared.
// Wave w owns disjoint (l,k) pairs -> epilogue/stores fully wave-local:
//   w0: (2,2)            w1: (0,2),(1,2)
//   w2: (1,1),(2,1)      w3: (0,0),(1,0),(2,0),(0,1)
// Lane: n = lane>>4 (NK), c = lane&15 (C); channel = n*16+c = lane.
// ---------------------------------------------------------------------------
__global__ __launch_bounds__(256, 4)
void conv_kernel(const float* __restrict__ sig0, const float* __restrict__ ker0,
                 const float* __restrict__ sig1, const float* __restrict__ ker1,
                 const float* __restrict__ sig2, const float* __restrict__ ker2,
                 const unsigned* __restrict__ pw, float* __restrict__ out){
  __shared__ __align__(16) float sig_lds[16*144];   // [p][m(9)][c(16)]
  __shared__ __align__(16) float kern_t[16*48];     // [p][n(4)][12] kd 0..8

  const int t    = threadIdx.x;
  const int w    = t >> 6;
  const int lane = t & 63;
  const int bv   = blockIdx.x;
  const size_t bvs = (size_t)bv;
  const int n = lane >> 4, c = lane & 15;

  // --- patch indices: wave-redundant, register-only (no barrier needed) ---
  // Detect int64 vs int32 storage from the safe first 32 words: odd words are
  // int64 high-halves (all zero) or int32 pn values (virtually never all zero).
  int row = 0;
  {
    const unsigned probe = (lane < 16) ? pw[2*lane + 1] : 0u;
    const unsigned long long nz = __ballot(probe != 0u);
    const size_t s = (nz == 0ull) ? 2 : 1;          // 2 = int64, 1 = int32
    if(lane < 16){
      const size_t e = ((size_t)bv*16 + lane)*2;
      const int pb = (int)pw[(e+0)*s] & 3;
      const int pn = (int)pw[(e+1)*s] & (N_DIM-1);
      row = pb*N_DIM + pn;
    }
  }

  // --- staging, split across waves ---
  if(w == 3){
    // kernels, transposed to [p][n][12]
    if(lane < 16){
      float4 v = ((const float4*)(ker0 + bvs*64))[lane];
      float* d = &kern_t[lane*48];
      d[0]=v.x; d[12]=v.y; d[24]=v.z; d[36]=v.w;
    }
    if(lane < 48){
      float4 v = ((const float4*)(ker1 + bvs*192))[lane];
      const int p = lane/3, kd = lane%3;
      float* d = &kern_t[p*48 + 1 + kd];
      d[0]=v.x; d[12]=v.y; d[24]=v.z; d[36]=v.w;
    }
    for(int j=lane; j<80; j+=64){
      float4 v = ((const float4*)(ker2 + bvs*320))[j];
      const int p = j/5, kd = j%5;
      float* d = &kern_t[p*48 + 4 + kd];
      d[0]=v.x; d[12]=v.y; d[24]=v.z; d[36]=v.w;
    }
  } else {
    // signal gather: 16 patches x 36 float4; 3 float4 per lane per wave
    const int p = lane >> 2, q = lane & 3;
    const size_t ro = (size_t)__shfl(row, p);
    float4* dst = ((float4*)sig_lds) + p*36;
    if(w == 0){
      dst[q]    = ((const float4*)(sig0 + ro*16))[q];
      dst[q+4]  = ((const float4*)(sig1 + ro*48))[q];
      dst[q+8]  = ((const float4*)(sig1 + ro*48))[q+4];
    } else if(w == 1){
      dst[q+12] = ((const float4*)(sig1 + ro*48))[q+8];
      dst[q+16] = ((const float4*)(sig2 + ro*80))[q];
      dst[q+20] = ((const float4*)(sig2 + ro*80))[q+4];
    } else {
      dst[q+24] = ((const float4*)(sig2 + ro*80))[q+8];
      dst[q+28] = ((const float4*)(sig2 + ro*80))[q+12];
      dst[q+32] = ((const float4*)(sig2 + ro*80))[q+16];
    }
  }
  __syncthreads();

  // d_out regions: o0 [BV][1][192] @0 ; o1 [BV][3][384] ; o2 [BV][5][384]
  float* o0 = out;
  float* o1 = out + 3145728;
  float* o2 = out + 22020096;

  if(w == 0){
    // (l=2,k=2): y[m4-8][kd4-8]
    float y[5][5] = {};
    #pragma unroll
    for(int p=0;p<16;++p){
      float s[5], kk[5];
      #pragma unroll
      for(int i=0;i<5;++i) s[i] = sig_lds[p*144 + (4+i)*16 + c];
      float4 a = *(const float4*)&kern_t[p*48 + n*12 + 4];
      kk[0]=a.x; kk[1]=a.y; kk[2]=a.z; kk[3]=a.w; kk[4]=kern_t[p*48 + n*12 + 8];
      #pragma unroll
      for(int i=0;i<5;++i)
        #pragma unroll
        for(int j=0;j<5;++j) y[i][j] += s[i]*kk[j];
    }
    cg_store<2,2,0,192,128>(y, o0, bvs, lane);
    cg_store<2,2,1,384,320>(y, o1, bvs, lane);
    cg_store<2,2,2,384,320>(y, o2, bvs, lane);
  } else if(w == 1){
    // (l=0,k=2) direct + (l=1,k=2)
    float y0[1][5] = {}, y1[3][5] = {};
    #pragma unroll
    for(int p=0;p<16;++p){
      float s0v = sig_lds[p*144 + c];
      float s[3], kk[5];
      #pragma unroll
      for(int i=0;i<3;++i) s[i] = sig_lds[p*144 + (1+i)*16 + c];
      float4 a = *(const float4*)&kern_t[p*48 + n*12 + 4];
      kk[0]=a.x; kk[1]=a.y; kk[2]=a.z; kk[3]=a.w; kk[4]=kern_t[p*48 + n*12 + 8];
      #pragma unroll
      for(int j=0;j<5;++j){
        y0[0][j] += s0v*kk[j];
        #pragma unroll
        for(int i=0;i<3;++i) y1[i][j] += s[i]*kk[j];
      }
    }
    #pragma unroll
    for(int kd=0;kd<5;++kd) o2[(bvs*5 + kd)*384 + lane] = y0[0][kd];  // (0,2)@0
    cg_store<1,2,1,384,192>(y1, o1, bvs, lane);
    cg_store<1,2,2,384,128>(y1, o2, bvs, lane);
  } else if(w == 2){
    // (l=1,k=1) + (l=2,k=1)
    float y11[3][3] = {}, y21[5][3] = {};
    #pragma unroll
    for(int p=0;p<16;++p){
      float s1[3], s2[5], kk[3];
      #pragma unroll
      for(int i=0;i<3;++i) s1[i] = sig_lds[p*144 + (1+i)*16 + c];
      #pragma unroll
      for(int i=0;i<5;++i) s2[i] = sig_lds[p*144 + (4+i)*16 + c];
      #pragma unroll
      for(int j=0;j<3;++j) kk[j] = kern_t[p*48 + n*12 + 1 + j];
      #pragma unroll
      for(int j=0;j<3;++j){
        #pragma unroll
        for(int i=0;i<3;++i) y11[i][j] += s1[i]*kk[j];
        #pragma unroll
        for(int i=0;i<5;++i) y21[i][j] += s2[i]*kk[j];
      }
    }
    cg_store<1,1,0,192, 64>(y11, o0, bvs, lane);
    cg_store<1,1,1,384,128>(y11, o1, bvs, lane);
    cg_store<1,1,2,384, 64>(y11, o2, bvs, lane);
    cg_store<2,1,1,384,256>(y21, o1, bvs, lane);
    cg_store<2,1,2,384,256>(y21, o2, bvs, lane);
  } else {
    // (0,0),(1,0),(2,0) [k=0] + (0,1) direct
    float y00 = 0.f, y01[3] = {};
    float y10[3][1] = {}, y20[5][1] = {};
    #pragma unroll
    for(int p=0;p<16;++p){
      float s0v = sig_lds[p*144 + c];
      float sm[8];
      #pragma unroll
      for(int i=0;i<8;++i) sm[i] = sig_lds[p*144 + (1+i)*16 + c];
      float k0v = kern_t[p*48 + n*12];
      float k13[3];
      #pragma unroll
      for(int j=0;j<3;++j) k13[j] = kern_t[p*48 + n*12 + 1 + j];
      y00 += s0v*k0v;
      #pragma unroll
      for(int j=0;j<3;++j) y01[j] += s0v*k13[j];
      #pragma unroll
      for(int i=0;i<3;++i) y10[i][0] += sm[i]*k0v;
      #pragma unroll
      for(int i=0;i<5;++i) y20[i][0] += sm[3+i]*k0v;
    }
    o0[bvs*192 + lane] = y00;                                          // (0,0)@0
    #pragma unroll
    for(int kd=0;kd<3;++kd) o1[(bvs*3 + kd)*384 + lane] = y01[kd];     // (0,1)@0
    cg_store<1,0,1,384, 64>(y10, o1, bvs, lane);
    cg_store<2,0,2,384,192>(y20, o2, bvs, lane);
  }
}

extern "C" void kernel_launch(void* const* d_in, const int* in_sizes, int n_in,
                              void* d_out, int out_size, void* d_ws, size_t ws_size,
                              hipStream_t stream) {
  const float *s0=nullptr,*s1=nullptr,*s2=nullptr,*k0=nullptr,*k1=nullptr,*k2=nullptr;
  const void* pidx=nullptr;
  if(n_in >= 7){
    s0=(const float*)d_in[0]; k0=(const float*)d_in[1];
    s1=(const float*)d_in[2]; k1=(const float*)d_in[3];
    s2=(const float*)d_in[4]; k2=(const float*)d_in[5];
    pidx=d_in[6];
  }
  for(int i=0;i<n_in;++i){
    switch(in_sizes[i]){
      case 262144:  s0=(const float*)d_in[i]; break;   // 4*4096*1*16
      case 786432:  s1=(const float*)d_in[i]; break;   // 4*4096*3*16
      case 1310720: s2=(const float*)d_in[i]; break;   // 4*4096*5*16
      case 1048576: k0=(const float*)d_in[i]; break;   // 4*4096*16*1*4
      case 3145728: k1=(const float*)d_in[i]; break;   // 4*4096*16*3*4
      case 5242880: k2=(const float*)d_in[i]; break;   // 4*4096*16*5*4
      case 524288:  pidx=d_in[i]; break;               // 4*4096*16*2
      default: break;
    }
  }

  conv_kernel<<<16384, 256, 0, stream>>>(s0, k0, s1, k1, s2, k2,
                                         (const unsigned*)pidx, (float*)d_out);
}